// Round 12
// baseline (527.405 us; speedup 1.0000x reference)
//
#include <hip/hip_runtime.h>
#include <hip/hip_fp16.h>
#include <math.h>

#define N_NODES 51200
#define N_EDGES 819200
#define NB 64
#define CAP 64  // max in-degree; Binomial(E,1/N) mean 16, P(>=64) ~ 1e-19

typedef _Float16 half8 __attribute__((ext_vector_type(8)));
typedef __attribute__((ext_vector_type(4))) float float4v;

__device__ __forceinline__ float eluf(float x) {
  return x > 0.f ? x : expm1f(x);
}

// Decode packed edge record {w0 = src|K<<16, w1 = half2(f0,f1)} for corner c.
__device__ __forceinline__ void dec2(int w0, int w1, int c, float& basf, int& Kc) {
  int K = w0 >> 16;  // src < 65536, K <= 18 -> w0 >= 0
  float f0 = __half2float(__ushort_as_half((unsigned short)(w1 & 0xFFFF)));
  float f1 = __half2float(__ushort_as_half((unsigned short)(((unsigned)w1) >> 16)));
  float b0 = (c & 2) ? f0 : 1.f - f0;
  float bv = (c & 1) ? f1 : 1.f - f1;
  Kc = K + (c >> 1) * 5 + (c & 1);
  basf = b0 * bv;
}

// Fire-and-forget packed fp16 LDS atomics: ds_pk_add_f16 (no return -> no
// dependency chain; HW serializes aliasing updates). Generic LDS pointer's
// low 32 bits are the DS byte address on AMDGCN.
__device__ __forceinline__ void pkadd16(unsigned* tp, float bf, int4 hv) {
  __half2 bas = __float2half2_rn(bf);
  const __half2* h = (const __half2*)&hv;
  __half2 d0 = __hmul2(bas, h[0]);
  __half2 d1 = __hmul2(bas, h[1]);
  __half2 d2 = __hmul2(bas, h[2]);
  __half2 d3 = __hmul2(bas, h[3]);
  unsigned addr = (unsigned)(size_t)tp;
  asm volatile("ds_pk_add_f16 %0, %1 offset:0\n\t"
               "ds_pk_add_f16 %0, %2 offset:4\n\t"
               "ds_pk_add_f16 %0, %3 offset:8\n\t"
               "ds_pk_add_f16 %0, %4 offset:12"
               :: "v"(addr), "v"(*(unsigned*)&d0), "v"(*(unsigned*)&d1),
                  "v"(*(unsigned*)&d2), "v"(*(unsigned*)&d3));
}
__device__ __forceinline__ void pkadd4(unsigned* tp, float bf, unsigned xv) {
  __half2 d = __hmul2(__float2half2_rn(bf), *(const __half2*)&xv);
  unsigned addr = (unsigned)(size_t)tp;
  asm volatile("ds_pk_add_f16 %0, %1" :: "v"(addr), "v"(*(unsigned*)&d));
}

// Prep: xcast (N x 7 fp32 -> N x 8 fp16) | W1T | W2T | zero gbuf. Grid 1852.
__global__ __launch_bounds__(256) void prep(const float* __restrict__ x,
                                            const float* __restrict__ W1,
                                            const float* __restrict__ root1,
                                            const float* __restrict__ W2,
                                            const float* __restrict__ root2,
                                            __half* __restrict__ xh,
                                            __half* __restrict__ W1T,
                                            __half* __restrict__ W2T,
                                            float* __restrict__ gbuf) {
  int b = blockIdx.x, tid = threadIdx.x;
  if (b < 1600) {                       // xcast: N*8 = 409600
    int idx = b * 256 + tid;
    int n = idx >> 3, j = idx & 7;
    xh[idx] = __float2half((j < 7) ? x[n * 7 + j] : 0.f);
  } else if (b < 1628) {                // W1T: 32 feats x 224 = 7168
    int idx = (b - 1600) * 256 + tid;
    int o = idx / 224, k = idx - o * 224;
    float v = 0.f;
    if (k < 200) {
      int cell = k >> 3, f = k & 7;
      if (f < 7) v = W1[(cell * 7 + f) * 32 + o];
    } else if (k < 207) {
      v = root1[(k - 200) * 32 + o];
    }
    W1T[idx] = __float2half(v);
  } else if (b < 1836) {                // W2T: 64 feats x 832 = 53248
    int idx = (b - 1628) * 256 + tid;
    int o = idx / 832, k = idx - o * 832;
    float v = (k < 800) ? W2[k * 64 + o] : root2[(k - 800) * 64 + o];
    W2T[idx] = __float2half(v);
  } else {                              // zero gbuf: 64*64 = 4096
    int idx = (b - 1836) * 256 + tid;
    gbuf[idx] = 0.f;
  }
}

// Build dst-CSR with fixed-capacity buckets; 4 edges per thread (4 independent
// atomic chains in flight). cnt doubles as degree.
__global__ __launch_bounds__(256) void scatter_eid(const int* __restrict__ ei,
                                                   const float* __restrict__ pseudo,
                                                   int* __restrict__ cnt,
                                                   int2* __restrict__ bucket) {
  int base = blockIdx.x * 1024 + threadIdx.x;
#pragma unroll
  for (int u = 0; u < 4; u++) {
    int e = base + u * 256;
    int src = ei[e], dst = ei[N_EDGES + e];
    float v0 = pseudo[2 * e] * 4.f;
    float v1 = pseudo[2 * e + 1] * 4.f;
    int lo0 = min(max((int)floorf(v0), 0), 3);
    int lo1 = min(max((int)floorf(v1), 0), 3);
    float f0 = v0 - (float)lo0, f1 = v1 - (float)lo1;
    int K = lo0 * 5 + lo1;  // corners at K, K+1, K+5, K+6
    unsigned short u0 = __half_as_ushort(__float2half(f0));
    unsigned short u1 = __half_as_ushort(__float2half(f1));
    int w0 = src | (K << 16);
    int w1 = (int)((unsigned)u0 | ((unsigned)u1 << 16));
    int slot = atomicAdd(&cnt[dst], 1);
    if (slot < CAP) bucket[(size_t)dst * CAP + slot] = make_int2(w0, w1);
  }
}

// Layer 1 fused: T[16 nodes][224 halves] in LDS; Phase A: 4 nodes in parallel
// per wave (lane = slot|corner|pair), software-pipelined edge loop, fire-and-
// forget ds_pk_add_f16 updates; then MFMA f16:
// h1 = elu( ([T | deg*x] @ [W1;root1]T) * invdeg + b1 ), fp16 out.
#define L1N 16
__global__ __launch_bounds__(256) void fused_l1(const int2* __restrict__ bucket,
                                                const int* __restrict__ cnt,
                                                const unsigned* __restrict__ xh,   // N x 4 dwords
                                                const __half* __restrict__ W1T,
                                                const float* __restrict__ b1,
                                                unsigned short* __restrict__ h1h) {
  __shared__ unsigned T[L1N * 112];  // 7.2 KB
  __shared__ float invdeg_s[L1N];
  int tid = threadIdx.x;
  int n0 = blockIdx.x * L1N;
  for (int idx = tid; idx < L1N * 112; idx += 256) T[idx] = 0u;
  if (tid < L1N) invdeg_s[tid] = 1.f / fmaxf((float)cnt[n0 + tid], 1.f);
  __syncthreads();
  // append max(deg,1)*x at dwords 100..103 (Phase A touches dwords < 100).
  if (tid < L1N * 4) {
    int row = tid >> 2, p = tid & 3;
    int n = n0 + row;
    float dgc = fmaxf((float)cnt[n], 1.f);
    unsigned xv = xh[n * 4 + p];
    __half2 h = __hmul2(*(const __half2*)&xv, __float2half2_rn(dgc));
    T[row * 112 + 100 + p] = *(unsigned*)&h;
  }
  int wv = tid >> 6, l = tid & 63;
  int slot = l >> 4, c = (l >> 2) & 3, p = l & 3;
  int nn = wv * 4 + slot;
  int n = n0 + nn;
  int dg = min(cnt[n], CAP);
  int dmax = dg;
  dmax = max(dmax, __shfl_xor(dmax, 16));
  dmax = max(dmax, __shfl_xor(dmax, 32));
  const int2* bk = bucket + (size_t)n * CAP;
  unsigned* Tr = &T[nn * 112];
  // pipeline prologue: records for iters 0,1; x-gathers for iter 0.
  int4 ra0 = *(const int4*)(bk + 0);
  int4 rb0 = *(const int4*)(bk + 2);
  int4 ra1 = *(const int4*)(bk + 4);
  int4 rb1 = *(const int4*)(bk + 6);
  unsigned xv0 = xh[(ra0.x & 0xFFFF) * 4 + p];
  unsigned xv1 = xh[(ra0.z & 0xFFFF) * 4 + p];
  unsigned xv2 = xh[(rb0.x & 0xFFFF) * 4 + p];
  unsigned xv3 = xh[(rb0.z & 0xFFFF) * 4 + p];
  for (int j = 0; j < dmax; j += 4) {
    int jp = min(j + 8, CAP - 4);               // records 2 iters ahead
    int4 ra2 = *(const int4*)(bk + jp);
    int4 rb2 = *(const int4*)(bk + jp + 2);
    unsigned nx0 = xh[(ra1.x & 0xFFFF) * 4 + p];  // gathers 1 iter ahead
    unsigned nx1 = xh[(ra1.z & 0xFFFF) * 4 + p];
    unsigned nx2 = xh[(rb1.x & 0xFFFF) * 4 + p];
    unsigned nx3 = xh[(rb1.z & 0xFFFF) * 4 + p];
    bool a0 = j < dg, a1 = j + 1 < dg, a2 = j + 2 < dg, a3 = j + 3 < dg;
    float bf; int Kc;
    if (a0) { dec2(ra0.x, ra0.y, c, bf, Kc); pkadd4(&Tr[Kc * 4 + p], bf, xv0); }
    if (a1) { dec2(ra0.z, ra0.w, c, bf, Kc); pkadd4(&Tr[Kc * 4 + p], bf, xv1); }
    if (a2) { dec2(rb0.x, rb0.y, c, bf, Kc); pkadd4(&Tr[Kc * 4 + p], bf, xv2); }
    if (a3) { dec2(rb0.z, rb0.w, c, bf, Kc); pkadd4(&Tr[Kc * 4 + p], bf, xv3); }
    ra0 = ra1; rb0 = rb1; ra1 = ra2; rb1 = rb2;
    xv0 = nx0; xv1 = nx1; xv2 = nx2; xv3 = nx3;
  }
  __syncthreads();
  // MFMA: waves 0,1 -> feat tiles 0,1; M=16 nodes, K=224 (7 iters).
  if (wv < 2) {
    int m = l & 15, quad = l >> 4;
    const char* abase = (const char*)T + m * 448 + quad * 16;
    const __half* bbase = W1T + (wv * 16 + m) * 224 + quad * 8;
    float4v acc = {0.f, 0.f, 0.f, 0.f};
#pragma unroll
    for (int it = 0; it < 7; it++) {
      half8 af = *(const half8*)(abase + it * 64);
      half8 bf = *(const half8*)(bbase + it * 32);
      acc = __builtin_amdgcn_mfma_f32_16x16x32_f16(af, bf, acc, 0, 0, 0);
    }
    int feat = wv * 16 + m;
    float bb = b1[feat];
#pragma unroll
    for (int r = 0; r < 4; r++) {
      int row = quad * 4 + r;
      float v = eluf(acc[r] * invdeg_s[row] + bb);
      h1h[(size_t)(n0 + row) * 32 + feat] = __half_as_ushort(__float2half(v));
    }
  }
}

// Layer 2 fused: T[16 nodes][840 halves] in LDS; Phase A: 4 nodes in parallel
// per wave (lane = slot|corner|quarter), software-pipelined edge loop, 4x
// ds_pk_add_f16 per lane (no RMW chain); MFMA f16 epilogue computes elu rows
// AND pool-reduces them into gbuf (one atomicAdd per block x feat).
#define L2N 16
__global__ __launch_bounds__(256) void fused_l2(const int2* __restrict__ bucket,
                                                const int* __restrict__ cnt,
                                                const unsigned* __restrict__ h1hu,  // N x 16 dwords
                                                const __half* __restrict__ W2T,
                                                const float* __restrict__ b2,
                                                float* __restrict__ gbuf) {
  __shared__ unsigned T[L2N * 420];  // 26.9 KB
  __shared__ float invdeg_s[L2N];
  int tid = threadIdx.x;
  int n0 = blockIdx.x * L2N;
  for (int idx = tid; idx < L2N * 420; idx += 256) T[idx] = 0u;
  if (tid < L2N) invdeg_s[tid] = 1.f / fmaxf((float)cnt[n0 + tid], 1.f);
  __syncthreads();
  // append max(deg,1)*h1 at dwords 400..415 (Phase A touches dwords < 400).
  {
    int row = tid >> 4, p = tid & 15;
    int n = n0 + row;
    float dgc = fmaxf((float)cnt[n], 1.f);
    unsigned hv = h1hu[(size_t)n * 16 + p];
    __half2 h = __hmul2(*(const __half2*)&hv, __float2half2_rn(dgc));
    T[row * 420 + 400 + p] = *(unsigned*)&h;
  }
  int wv = tid >> 6, l = tid & 63;
  int slot = l >> 4, c = (l >> 2) & 3, q = l & 3;
  int nn = wv * 4 + slot;
  int n = n0 + nn;
  int dg = min(cnt[n], CAP);
  int dmax = dg;
  dmax = max(dmax, __shfl_xor(dmax, 16));
  dmax = max(dmax, __shfl_xor(dmax, 32));
  const int2* bk = bucket + (size_t)n * CAP;
  unsigned* Tr = &T[nn * 420];
  const unsigned* h1q = h1hu + q * 4;
  // pipeline prologue: records for iters 0,1; h1-gathers for iter 0.
  int4 ra0 = *(const int4*)(bk + 0);
  int4 rb0 = *(const int4*)(bk + 2);
  int4 ra1 = *(const int4*)(bk + 4);
  int4 rb1 = *(const int4*)(bk + 6);
  int4 hv0 = *(const int4*)(h1q + (size_t)(ra0.x & 0xFFFF) * 16);
  int4 hv1 = *(const int4*)(h1q + (size_t)(ra0.z & 0xFFFF) * 16);
  int4 hv2 = *(const int4*)(h1q + (size_t)(rb0.x & 0xFFFF) * 16);
  int4 hv3 = *(const int4*)(h1q + (size_t)(rb0.z & 0xFFFF) * 16);
  for (int j = 0; j < dmax; j += 4) {
    int jp = min(j + 8, CAP - 4);               // records 2 iters ahead
    int4 ra2 = *(const int4*)(bk + jp);
    int4 rb2 = *(const int4*)(bk + jp + 2);
    int4 nh0 = *(const int4*)(h1q + (size_t)(ra1.x & 0xFFFF) * 16);  // 1 ahead
    int4 nh1 = *(const int4*)(h1q + (size_t)(ra1.z & 0xFFFF) * 16);
    int4 nh2 = *(const int4*)(h1q + (size_t)(rb1.x & 0xFFFF) * 16);
    int4 nh3 = *(const int4*)(h1q + (size_t)(rb1.z & 0xFFFF) * 16);
    bool a0 = j < dg, a1 = j + 1 < dg, a2 = j + 2 < dg, a3 = j + 3 < dg;
    float bf; int Kc;
    if (a0) { dec2(ra0.x, ra0.y, c, bf, Kc); pkadd16(&Tr[Kc * 16 + q * 4], bf, hv0); }
    if (a1) { dec2(ra0.z, ra0.w, c, bf, Kc); pkadd16(&Tr[Kc * 16 + q * 4], bf, hv1); }
    if (a2) { dec2(rb0.x, rb0.y, c, bf, Kc); pkadd16(&Tr[Kc * 16 + q * 4], bf, hv2); }
    if (a3) { dec2(rb0.z, rb0.w, c, bf, Kc); pkadd16(&Tr[Kc * 16 + q * 4], bf, hv3); }
    ra0 = ra1; rb0 = rb1; ra1 = ra2; rb1 = rb2;
    hv0 = nh0; hv1 = nh1; hv2 = nh2; hv3 = nh3;
  }
  __syncthreads();
  // MFMA: wave wv -> feats [wv*16, wv*16+16), K=832 (26 iters).
  int m = l & 15, quad = l >> 4;
  const char* abase = (const char*)T + m * 1680 + quad * 16;
  const __half* bbase = W2T + (size_t)(wv * 16 + m) * 832 + quad * 8;
  float4v acc = {0.f, 0.f, 0.f, 0.f};
  for (int it = 0; it < 26; it++) {
    half8 af = *(const half8*)(abase + it * 64);
    half8 bf = *(const half8*)(bbase + it * 32);
    acc = __builtin_amdgcn_mfma_f32_16x16x32_f16(af, bf, acc, 0, 0, 0);
  }
  int feat = wv * 16 + m;
  float bb = b2[feat];
  float psum = 0.f;
#pragma unroll
  for (int r = 0; r < 4; r++) {
    int node = quad * 4 + r;
    psum += eluf(acc[r] * invdeg_s[node] + bb);
  }
  // reduce over quad (nodes) -> full 16-node sum per feat; 800 nodes per
  // group and 800 % L2N == 0, so the whole block is in one group.
  psum += __shfl_xor(psum, 16);
  psum += __shfl_xor(psum, 32);
  if (l < 16) {
    int g = n0 / 800;
    atomicAdd(&gbuf[g * 64 + feat], psum);
  }
}

// FC(64->30) + log_softmax on pooled sums. gbuf holds per-group SUM of elu(h2);
// divide by slice count here. One block (64 thr) per group; lanes 0..29 active.
__global__ __launch_bounds__(64) void fc_ls(const float* __restrict__ gbuf,
                                            const int* __restrict__ slices,
                                            const float* __restrict__ fcw,
                                            const float* __restrict__ fcb,
                                            float* __restrict__ out) {
  int g = blockIdx.x;
  int l = threadIdx.x;
  float scale = 1.f / fmaxf((float)(slices[g + 1] - slices[g]), 1.f);
  float logit = -INFINITY;
  if (l < 30) {
    float acc = fcb[l];
    for (int i = 0; i < 64; i++) acc += gbuf[g * 64 + i] * scale * fcw[i * 30 + l];
    logit = acc;
  }
  float m = logit;
  for (int off = 16; off; off >>= 1) m = fmaxf(m, __shfl_xor(m, off, 32));
  float e = (l < 30) ? expf(logit - m) : 0.f;
  for (int off = 16; off; off >>= 1) e += __shfl_xor(e, off, 32);
  if (l < 30) out[g * 30 + l] = logit - m - logf(e);
}

extern "C" void kernel_launch(void* const* d_in, const int* in_sizes, int n_in,
                              void* d_out, int out_size, void* d_ws, size_t ws_size,
                              hipStream_t stream) {
  const float* x      = (const float*)d_in[0];
  const int*   ei     = (const int*)d_in[1];
  const float* pseudo = (const float*)d_in[2];
  const int*   slices = (const int*)d_in[3];
  const float* W1     = (const float*)d_in[4];
  const float* root1  = (const float*)d_in[5];
  const float* b1     = (const float*)d_in[6];
  const float* W2     = (const float*)d_in[7];
  const float* root2  = (const float*)d_in[8];
  const float* b2     = (const float*)d_in[9];
  const float* fcw    = (const float*)d_in[10];
  const float* fcb    = (const float*)d_in[11];
  float* out = (float*)d_out;

  char* ws = (char*)d_ws;
  int*      cnt    = (int*)ws;                                    // N ints
  int2*     bucket = (int2*)(cnt + N_NODES);                      // N*CAP int2 (26.2 MB)
  unsigned* h1h    = (unsigned*)(bucket + (size_t)N_NODES * CAP); // N*16 dwords (fp16 h1)
  float*    gbuf   = (float*)(h1h + (size_t)N_NODES * 16);        // 64*64 fp32
  unsigned* xh     = (unsigned*)(gbuf + 64 * 64);                 // N*4 dwords (fp16 x)
  __half*   W1T    = (__half*)(xh + (size_t)N_NODES * 4);         // 32*224
  __half*   W2T    = W1T + 32 * 224;                              // 64*832

  hipMemsetAsync(cnt, 0, N_NODES * sizeof(int), stream);

  prep<<<1852, 256, 0, stream>>>(x, W1, root1, W2, root2,
                                 (__half*)xh, W1T, W2T, gbuf);
  scatter_eid<<<N_EDGES / 1024, 256, 0, stream>>>(ei, pseudo, cnt, bucket);
  fused_l1<<<N_NODES / L1N, 256, 0, stream>>>(bucket, cnt, xh, W1T, b1,
                                              (unsigned short*)h1h);
  fused_l2<<<N_NODES / L2N, 256, 0, stream>>>(bucket, cnt, h1h, W2T, b2, gbuf);
  fc_ls<<<NB, 64, 0, stream>>>(gbuf, slices, fcw, fcb, out);
}

// Round 13
// 208.871 us; speedup vs baseline: 2.5250x; 2.5250x over previous
//
#include <hip/hip_runtime.h>
#include <hip/hip_fp16.h>
#include <math.h>

#define N_NODES 51200
#define N_EDGES 819200
#define NB 64
#define CAP 64  // max in-degree; Binomial(E,1/N) mean 16, P(>=64) ~ 1e-19

typedef _Float16 half8 __attribute__((ext_vector_type(8)));
typedef __attribute__((ext_vector_type(4))) float float4v;

__device__ __forceinline__ float eluf(float x) {
  return x > 0.f ? x : expm1f(x);
}

// Decode packed edge record {w0 = src|K<<16, w1 = half2(f0,f1)} for corner c.
__device__ __forceinline__ void dec2(int w0, int w1, int c, float& basf, int& Kc) {
  int K = w0 >> 16;  // src < 65536, K <= 18 -> w0 >= 0
  float f0 = __half2float(__ushort_as_half((unsigned short)(w1 & 0xFFFF)));
  float f1 = __half2float(__ushort_as_half((unsigned short)(((unsigned)w1) >> 16)));
  float b0 = (c & 2) ? f0 : 1.f - f0;
  float bv = (c & 1) ? f1 : 1.f - f1;
  Kc = K + (c >> 1) * 5 + (c & 1);
  basf = b0 * bv;
}

// 16B LDS RMW: T row chunk [Kc*16 + q*4 .. +3] (4x half2 fma).
// NOTE: the serialization of consecutive rmw16 calls is REQUIRED for
// correctness: different lanes' cells for different unroll positions can
// alias; lockstep sequencing makes read-after-write correct. Do not batch.
__device__ __forceinline__ void rmw16(unsigned* Tr, int Kc, int q, float bf, int4 hv) {
  __half2 bas = __float2half2_rn(bf);
  __half2* tp = (__half2*)&Tr[Kc * 16 + q * 4];
  const __half2* h = (const __half2*)&hv;
  __half2 t0 = tp[0], t1 = tp[1], t2 = tp[2], t3 = tp[3];
  tp[0] = __hfma2(bas, h[0], t0);
  tp[1] = __hfma2(bas, h[1], t1);
  tp[2] = __hfma2(bas, h[2], t2);
  tp[3] = __hfma2(bas, h[3], t3);
}

// Prep: xcast (N x 7 fp32 -> N x 8 fp16) | W1T | W2T | zero gbuf. Grid 1852.
__global__ __launch_bounds__(256) void prep(const float* __restrict__ x,
                                            const float* __restrict__ W1,
                                            const float* __restrict__ root1,
                                            const float* __restrict__ W2,
                                            const float* __restrict__ root2,
                                            __half* __restrict__ xh,
                                            __half* __restrict__ W1T,
                                            __half* __restrict__ W2T,
                                            float* __restrict__ gbuf) {
  int b = blockIdx.x, tid = threadIdx.x;
  if (b < 1600) {                       // xcast: N*8 = 409600
    int idx = b * 256 + tid;
    int n = idx >> 3, j = idx & 7;
    xh[idx] = __float2half((j < 7) ? x[n * 7 + j] : 0.f);
  } else if (b < 1628) {                // W1T: 32 feats x 224 = 7168
    int idx = (b - 1600) * 256 + tid;
    int o = idx / 224, k = idx - o * 224;
    float v = 0.f;
    if (k < 200) {
      int cell = k >> 3, f = k & 7;
      if (f < 7) v = W1[(cell * 7 + f) * 32 + o];
    } else if (k < 207) {
      v = root1[(k - 200) * 32 + o];
    }
    W1T[idx] = __float2half(v);
  } else if (b < 1836) {                // W2T: 64 feats x 832 = 53248
    int idx = (b - 1628) * 256 + tid;
    int o = idx / 832, k = idx - o * 832;
    float v = (k < 800) ? W2[k * 64 + o] : root2[(k - 800) * 64 + o];
    W2T[idx] = __float2half(v);
  } else {                              // zero gbuf: 64*64 = 4096
    int idx = (b - 1836) * 256 + tid;
    gbuf[idx] = 0.f;
  }
}

// Build dst-CSR with fixed-capacity buckets; 8 edges per thread (8 independent
// atomic chains in flight). cnt doubles as degree.
__global__ __launch_bounds__(256) void scatter_eid(const int* __restrict__ ei,
                                                   const float* __restrict__ pseudo,
                                                   int* __restrict__ cnt,
                                                   int2* __restrict__ bucket) {
  int base = blockIdx.x * 2048 + threadIdx.x;
#pragma unroll
  for (int u = 0; u < 8; u++) {
    int e = base + u * 256;
    int src = ei[e], dst = ei[N_EDGES + e];
    float v0 = pseudo[2 * e] * 4.f;
    float v1 = pseudo[2 * e + 1] * 4.f;
    int lo0 = min(max((int)floorf(v0), 0), 3);
    int lo1 = min(max((int)floorf(v1), 0), 3);
    float f0 = v0 - (float)lo0, f1 = v1 - (float)lo1;
    int K = lo0 * 5 + lo1;  // corners at K, K+1, K+5, K+6
    unsigned short u0 = __half_as_ushort(__float2half(f0));
    unsigned short u1 = __half_as_ushort(__float2half(f1));
    int w0 = src | (K << 16);
    int w1 = (int)((unsigned)u0 | ((unsigned)u1 << 16));
    int slot = atomicAdd(&cnt[dst], 1);
    if (slot < CAP) bucket[(size_t)dst * CAP + slot] = make_int2(w0, w1);
  }
}

// Layer 1 fused: T[16 nodes][224 halves] in LDS; Phase A: 4 nodes in parallel
// per wave (lane = slot|corner|pair), software-pipelined edge loop (records
// prefetched 2 iters ahead, x-gathers 1 iter ahead); then MFMA f16:
// h1 = elu( ([T | deg*x] @ [W1;root1]T) * invdeg + b1 ), fp16 out.
#define L1N 16
__global__ __launch_bounds__(256) void fused_l1(const int2* __restrict__ bucket,
                                                const int* __restrict__ cnt,
                                                const unsigned* __restrict__ xh,   // N x 4 dwords
                                                const __half* __restrict__ W1T,
                                                const float* __restrict__ b1,
                                                unsigned short* __restrict__ h1h) {
  __shared__ unsigned T[L1N * 112];  // 7.2 KB
  __shared__ float invdeg_s[L1N];
  int tid = threadIdx.x;
  int n0 = blockIdx.x * L1N;
  for (int idx = tid; idx < L1N * 112; idx += 256) T[idx] = 0u;
  if (tid < L1N) invdeg_s[tid] = 1.f / fmaxf((float)cnt[n0 + tid], 1.f);
  __syncthreads();
  // append max(deg,1)*x at dwords 100..103 (Phase A touches dwords < 100).
  if (tid < L1N * 4) {
    int row = tid >> 2, p = tid & 3;
    int n = n0 + row;
    float dgc = fmaxf((float)cnt[n], 1.f);
    unsigned xv = xh[n * 4 + p];
    __half2 h = __hmul2(*(const __half2*)&xv, __float2half2_rn(dgc));
    T[row * 112 + 100 + p] = *(unsigned*)&h;
  }
  int wv = tid >> 6, l = tid & 63;
  int slot = l >> 4, c = (l >> 2) & 3, p = l & 3;
  int nn = wv * 4 + slot;
  int n = n0 + nn;
  int dg = min(cnt[n], CAP);
  int dmax = dg;
  dmax = max(dmax, __shfl_xor(dmax, 16));
  dmax = max(dmax, __shfl_xor(dmax, 32));
  const int2* bk = bucket + (size_t)n * CAP;
  unsigned* Tr = &T[nn * 112];
  // pipeline prologue: records for iters 0,1; x-gathers for iter 0.
  int4 ra0 = *(const int4*)(bk + 0);
  int4 rb0 = *(const int4*)(bk + 2);
  int4 ra1 = *(const int4*)(bk + 4);
  int4 rb1 = *(const int4*)(bk + 6);
  unsigned xv0 = xh[(ra0.x & 0xFFFF) * 4 + p];
  unsigned xv1 = xh[(ra0.z & 0xFFFF) * 4 + p];
  unsigned xv2 = xh[(rb0.x & 0xFFFF) * 4 + p];
  unsigned xv3 = xh[(rb0.z & 0xFFFF) * 4 + p];
  for (int j = 0; j < dmax; j += 4) {
    int jp = min(j + 8, CAP - 4);               // records 2 iters ahead
    int4 ra2 = *(const int4*)(bk + jp);
    int4 rb2 = *(const int4*)(bk + jp + 2);
    unsigned nx0 = xh[(ra1.x & 0xFFFF) * 4 + p];  // gathers 1 iter ahead
    unsigned nx1 = xh[(ra1.z & 0xFFFF) * 4 + p];
    unsigned nx2 = xh[(rb1.x & 0xFFFF) * 4 + p];
    unsigned nx3 = xh[(rb1.z & 0xFFFF) * 4 + p];
    bool a0 = j < dg, a1 = j + 1 < dg, a2 = j + 2 < dg, a3 = j + 3 < dg;
    float bf; int Kc;
    if (a0) { dec2(ra0.x, ra0.y, c, bf, Kc);
      __half2* tp = (__half2*)&Tr[Kc * 4 + p];
      *tp = __hfma2(__float2half2_rn(bf), *(const __half2*)&xv0, *tp); }
    if (a1) { dec2(ra0.z, ra0.w, c, bf, Kc);
      __half2* tp = (__half2*)&Tr[Kc * 4 + p];
      *tp = __hfma2(__float2half2_rn(bf), *(const __half2*)&xv1, *tp); }
    if (a2) { dec2(rb0.x, rb0.y, c, bf, Kc);
      __half2* tp = (__half2*)&Tr[Kc * 4 + p];
      *tp = __hfma2(__float2half2_rn(bf), *(const __half2*)&xv2, *tp); }
    if (a3) { dec2(rb0.z, rb0.w, c, bf, Kc);
      __half2* tp = (__half2*)&Tr[Kc * 4 + p];
      *tp = __hfma2(__float2half2_rn(bf), *(const __half2*)&xv3, *tp); }
    ra0 = ra1; rb0 = rb1; ra1 = ra2; rb1 = rb2;
    xv0 = nx0; xv1 = nx1; xv2 = nx2; xv3 = nx3;
  }
  __syncthreads();
  // MFMA: waves 0,1 -> feat tiles 0,1; M=16 nodes, K=224 (7 iters).
  if (wv < 2) {
    int m = l & 15, quad = l >> 4;
    const char* abase = (const char*)T + m * 448 + quad * 16;
    const __half* bbase = W1T + (wv * 16 + m) * 224 + quad * 8;
    float4v acc = {0.f, 0.f, 0.f, 0.f};
#pragma unroll
    for (int it = 0; it < 7; it++) {
      half8 af = *(const half8*)(abase + it * 64);
      half8 bf = *(const half8*)(bbase + it * 32);
      acc = __builtin_amdgcn_mfma_f32_16x16x32_f16(af, bf, acc, 0, 0, 0);
    }
    int feat = wv * 16 + m;
    float bb = b1[feat];
#pragma unroll
    for (int r = 0; r < 4; r++) {
      int row = quad * 4 + r;
      float v = eluf(acc[r] * invdeg_s[row] + bb);
      h1h[(size_t)(n0 + row) * 32 + feat] = __half_as_ushort(__float2half(v));
    }
  }
}

// Layer 2 fused: T[16 nodes][840 halves] in LDS; Phase A: 4 nodes in parallel
// per wave (lane = slot|corner|quarter, 16B b128 RMW), software-pipelined
// edge loop; MFMA f16 epilogue computes elu rows AND pool-reduces them into
// gbuf via one atomicAdd per (block, feat). h2 is never materialized.
#define L2N 16
__global__ __launch_bounds__(256) void fused_l2(const int2* __restrict__ bucket,
                                                const int* __restrict__ cnt,
                                                const unsigned* __restrict__ h1hu,  // N x 16 dwords
                                                const __half* __restrict__ W2T,
                                                const float* __restrict__ b2,
                                                float* __restrict__ gbuf) {
  __shared__ unsigned T[L2N * 420];  // 26.9 KB
  __shared__ float invdeg_s[L2N];
  int tid = threadIdx.x;
  int n0 = blockIdx.x * L2N;
  for (int idx = tid; idx < L2N * 420; idx += 256) T[idx] = 0u;
  if (tid < L2N) invdeg_s[tid] = 1.f / fmaxf((float)cnt[n0 + tid], 1.f);
  __syncthreads();
  // append max(deg,1)*h1 at dwords 400..415 (Phase A touches dwords < 400).
  {
    int row = tid >> 4, p = tid & 15;
    int n = n0 + row;
    float dgc = fmaxf((float)cnt[n], 1.f);
    unsigned hv = h1hu[(size_t)n * 16 + p];
    __half2 h = __hmul2(*(const __half2*)&hv, __float2half2_rn(dgc));
    T[row * 420 + 400 + p] = *(unsigned*)&h;
  }
  int wv = tid >> 6, l = tid & 63;
  int slot = l >> 4, c = (l >> 2) & 3, q = l & 3;
  int nn = wv * 4 + slot;
  int n = n0 + nn;
  int dg = min(cnt[n], CAP);
  int dmax = dg;
  dmax = max(dmax, __shfl_xor(dmax, 16));
  dmax = max(dmax, __shfl_xor(dmax, 32));
  const int2* bk = bucket + (size_t)n * CAP;
  unsigned* Tr = &T[nn * 420];
  const unsigned* h1q = h1hu + q * 4;
  // pipeline prologue: records for iters 0,1; h1-gathers for iter 0.
  int4 ra0 = *(const int4*)(bk + 0);
  int4 rb0 = *(const int4*)(bk + 2);
  int4 ra1 = *(const int4*)(bk + 4);
  int4 rb1 = *(const int4*)(bk + 6);
  int4 hv0 = *(const int4*)(h1q + (size_t)(ra0.x & 0xFFFF) * 16);
  int4 hv1 = *(const int4*)(h1q + (size_t)(ra0.z & 0xFFFF) * 16);
  int4 hv2 = *(const int4*)(h1q + (size_t)(rb0.x & 0xFFFF) * 16);
  int4 hv3 = *(const int4*)(h1q + (size_t)(rb0.z & 0xFFFF) * 16);
  for (int j = 0; j < dmax; j += 4) {
    int jp = min(j + 8, CAP - 4);               // records 2 iters ahead
    int4 ra2 = *(const int4*)(bk + jp);
    int4 rb2 = *(const int4*)(bk + jp + 2);
    int4 nh0 = *(const int4*)(h1q + (size_t)(ra1.x & 0xFFFF) * 16);  // 1 ahead
    int4 nh1 = *(const int4*)(h1q + (size_t)(ra1.z & 0xFFFF) * 16);
    int4 nh2 = *(const int4*)(h1q + (size_t)(rb1.x & 0xFFFF) * 16);
    int4 nh3 = *(const int4*)(h1q + (size_t)(rb1.z & 0xFFFF) * 16);
    bool a0 = j < dg, a1 = j + 1 < dg, a2 = j + 2 < dg, a3 = j + 3 < dg;
    float bf; int Kc;
    if (a0) { dec2(ra0.x, ra0.y, c, bf, Kc); rmw16(Tr, Kc, q, bf, hv0); }
    if (a1) { dec2(ra0.z, ra0.w, c, bf, Kc); rmw16(Tr, Kc, q, bf, hv1); }
    if (a2) { dec2(rb0.x, rb0.y, c, bf, Kc); rmw16(Tr, Kc, q, bf, hv2); }
    if (a3) { dec2(rb0.z, rb0.w, c, bf, Kc); rmw16(Tr, Kc, q, bf, hv3); }
    ra0 = ra1; rb0 = rb1; ra1 = ra2; rb1 = rb2;
    hv0 = nh0; hv1 = nh1; hv2 = nh2; hv3 = nh3;
  }
  __syncthreads();
  // MFMA: wave wv -> feats [wv*16, wv*16+16), K=832 (26 iters).
  int m = l & 15, quad = l >> 4;
  const char* abase = (const char*)T + m * 1680 + quad * 16;
  const __half* bbase = W2T + (size_t)(wv * 16 + m) * 832 + quad * 8;
  float4v acc = {0.f, 0.f, 0.f, 0.f};
  for (int it = 0; it < 26; it++) {
    half8 af = *(const half8*)(abase + it * 64);
    half8 bf = *(const half8*)(bbase + it * 32);
    acc = __builtin_amdgcn_mfma_f32_16x16x32_f16(af, bf, acc, 0, 0, 0);
  }
  int feat = wv * 16 + m;
  float bb = b2[feat];
  float psum = 0.f;
#pragma unroll
  for (int r = 0; r < 4; r++) {
    int node = quad * 4 + r;
    psum += eluf(acc[r] * invdeg_s[node] + bb);
  }
  // reduce over quad (nodes) -> full 16-node sum per feat; 800 nodes per
  // group and 800 % L2N == 0, so the whole block is in one group.
  psum += __shfl_xor(psum, 16);
  psum += __shfl_xor(psum, 32);
  if (l < 16) {
    int g = n0 / 800;
    atomicAdd(&gbuf[g * 64 + feat], psum);
  }
}

// FC(64->30) + log_softmax on pooled sums. gbuf holds per-group SUM of elu(h2);
// divide by slice count here. One block (64 thr) per group; lanes 0..29 active.
__global__ __launch_bounds__(64) void fc_ls(const float* __restrict__ gbuf,
                                            const int* __restrict__ slices,
                                            const float* __restrict__ fcw,
                                            const float* __restrict__ fcb,
                                            float* __restrict__ out) {
  int g = blockIdx.x;
  int l = threadIdx.x;
  float scale = 1.f / fmaxf((float)(slices[g + 1] - slices[g]), 1.f);
  float logit = -INFINITY;
  if (l < 30) {
    float acc = fcb[l];
    for (int i = 0; i < 64; i++) acc += gbuf[g * 64 + i] * scale * fcw[i * 30 + l];
    logit = acc;
  }
  float m = logit;
  for (int off = 16; off; off >>= 1) m = fmaxf(m, __shfl_xor(m, off, 32));
  float e = (l < 30) ? expf(logit - m) : 0.f;
  for (int off = 16; off; off >>= 1) e += __shfl_xor(e, off, 32);
  if (l < 30) out[g * 30 + l] = logit - m - logf(e);
}

extern "C" void kernel_launch(void* const* d_in, const int* in_sizes, int n_in,
                              void* d_out, int out_size, void* d_ws, size_t ws_size,
                              hipStream_t stream) {
  const float* x      = (const float*)d_in[0];
  const int*   ei     = (const int*)d_in[1];
  const float* pseudo = (const float*)d_in[2];
  const int*   slices = (const int*)d_in[3];
  const float* W1     = (const float*)d_in[4];
  const float* root1  = (const float*)d_in[5];
  const float* b1     = (const float*)d_in[6];
  const float* W2     = (const float*)d_in[7];
  const float* root2  = (const float*)d_in[8];
  const float* b2     = (const float*)d_in[9];
  const float* fcw    = (const float*)d_in[10];
  const float* fcb    = (const float*)d_in[11];
  float* out = (float*)d_out;

  char* ws = (char*)d_ws;
  int*      cnt    = (int*)ws;                                    // N ints
  int2*     bucket = (int2*)(cnt + N_NODES);                      // N*CAP int2 (26.2 MB)
  unsigned* h1h    = (unsigned*)(bucket + (size_t)N_NODES * CAP); // N*16 dwords (fp16 h1)
  float*    gbuf   = (float*)(h1h + (size_t)N_NODES * 16);        // 64*64 fp32
  unsigned* xh     = (unsigned*)(gbuf + 64 * 64);                 // N*4 dwords (fp16 x)
  __half*   W1T    = (__half*)(xh + (size_t)N_NODES * 4);         // 32*224
  __half*   W2T    = W1T + 32 * 224;                              // 64*832

  hipMemsetAsync(cnt, 0, N_NODES * sizeof(int), stream);

  prep<<<1852, 256, 0, stream>>>(x, W1, root1, W2, root2,
                                 (__half*)xh, W1T, W2T, gbuf);
  scatter_eid<<<N_EDGES / 2048, 256, 0, stream>>>(ei, pseudo, cnt, bucket);
  fused_l1<<<N_NODES / L1N, 256, 0, stream>>>(bucket, cnt, xh, W1T, b1,
                                              (unsigned short*)h1h);
  fused_l2<<<N_NODES / L2N, 256, 0, stream>>>(bucket, cnt, h1h, W2T, b2, gbuf);
  fc_ls<<<NB, 64, 0, stream>>>(gbuf, slices, fcw, fcb, out);
}